// Round 9
// baseline (202.981 us; speedup 1.0000x reference)
//
#include <hip/hip_runtime.h>

// Multiresolution hash encoding, MI355X. Round 9.
// R8 post-mortem: padded-bin scatter is ~free (3-5us) -- kept. But inlining the
// overflow-cleanup (__noinline__ call) into hashenc_sorted forced ABI-pessimal
// regalloc: 108 VGPR, 15% occupancy, main kernel 133->161us. Fix: cleanup gets
// its own tiny dispatch; hashenc_sorted is the bare R6 body (48 VGPR) with
// launch_bounds(256,8) now satisfiable, and nontemporal row stores restored
// (R6: 100MB write vs 130MB plain).

constexpr int      kT      = 524288;     // 2^19 rows per level
constexpr unsigned kMask   = kT - 1;
constexpr int      kB      = 262144;
constexpr unsigned kP1     = 2654435761u;
constexpr unsigned kP2     = 805459861u;
constexpr int      kBins   = 4096;
constexpr int      kCap    = 128;        // slots per bin (2 waves)
constexpr int      kOvfCap = 65536;      // overflow list capacity (never filled)

typedef float f32x4 __attribute__((ext_vector_type(4)));

__device__ __forceinline__ unsigned morton12(float x0, float x1, float x2) {
    unsigned a = min(15u, (unsigned)(x0 * 16.0f));
    unsigned b = min(15u, (unsigned)(x1 * 16.0f));
    unsigned c = min(15u, (unsigned)(x2 * 16.0f));
    unsigned key = 0;
#pragma unroll
    for (int i = 3; i >= 0; --i)
        key = (key << 3) | (((a >> i) & 1u) << 2) | (((b >> i) & 1u) << 1) | ((c >> i) & 1u);
    return key;
}

// ---- main compute body: R5/R6 pair-load structure (dim0 prime==1) ----
__device__ __forceinline__ void hashenc_body(const float x0, const float x1, const float x2,
                                             const f32x4* __restrict__ tab4base,
                                             f32x4* __restrict__ out, const unsigned sid) {
    f32x4 o[8];
    // floor(16 * b^l), b = 2^(1/3): rounding-traced, verified (absmax 4.8e-7)
    constexpr float kResF[16] = {16, 20, 25, 32, 40, 50, 64, 80,
                                 101, 128, 161, 203, 256, 322, 406, 512};
#pragma unroll
    for (int l = 0; l < 16; ++l) {
        const float res = kResF[l];
        const float s0 = x0 * res, s1 = x1 * res, s2 = x2 * res;
        const float f0 = floorf(s0), f1 = floorf(s1), f2 = floorf(s2);
        const float r0 = s0 - f0, r1 = s1 - f1, r2 = s2 - f2;
        const unsigned c0 = (unsigned)f0;
        const unsigned h1a = (unsigned)f1 * kP1, h1b = h1a + kP1;
        const unsigned h2a = (unsigned)f2 * kP2, h2b = h2a + kP2;
        const float w0a = 1.0f - r0, w1a = 1.0f - r1, w2a = 1.0f - r2;
        const f32x4* __restrict__ tab4 = tab4base + (size_t)l * (kT / 2);
        float a0 = 0.0f, a1 = 0.0f;
#pragma unroll
        for (int q = 0; q < 4; ++q) {  // (y,z) corner combos
            const unsigned g = ((q & 1) ? h1b : h1a) ^ ((q & 2) ? h2b : h2a);
            const unsigned i0 = (c0 ^ g) & kMask;
            const unsigned i1 = ((c0 + 1u) ^ g) & kMask;
            const f32x4 A = tab4[i0 >> 1];
            const f32x4 B = tab4[i1 >> 1];  // same line as A when c0 even
            const float p0x = (i0 & 1) ? A.z : A.x;
            const float p0y = (i0 & 1) ? A.w : A.y;
            const float p1x = (i1 & 1) ? B.z : B.x;
            const float p1y = (i1 & 1) ? B.w : B.y;
            const float wyz = ((q & 1) ? r1 : w1a) * ((q & 2) ? r2 : w2a);
            const float wl = wyz * w0a;
            const float wr = wyz * r0;
            a0 = fmaf(wl, p0x, fmaf(wr, p1x, a0));
            a1 = fmaf(wl, p0y, fmaf(wr, p1y, a1));
        }
        if (l & 1) { o[l >> 1].z = a0; o[l >> 1].w = a1; }
        else       { o[l >> 1].x = a0; o[l >> 1].y = a1; }
    }
    f32x4* op = out + (size_t)sid * 8;
#pragma unroll
    for (int k = 0; k < 8; ++k) __builtin_nontemporal_store(o[k], op + k);
}

__global__ __launch_bounds__(256) void scatter_kernel(const float* __restrict__ x,
                                                      unsigned* __restrict__ cnt,
                                                      f32x4* __restrict__ xsort,
                                                      f32x4* __restrict__ ovf) {
    const int i = blockIdx.x * 256 + threadIdx.x;
    const float x0 = x[3 * i], x1 = x[3 * i + 1], x2 = x[3 * i + 2];
    const unsigned key = morton12(x0, x1, x2);
    const unsigned slot = atomicAdd(&cnt[key], 1u);
    f32x4 v;
    v.x = x0; v.y = x1; v.z = x2; v.w = __uint_as_float((unsigned)i);
    if (slot < (unsigned)kCap) {
        xsort[key * kCap + slot] = v;
    } else {
        const unsigned o = atomicAdd(&cnt[kBins], 1u);
        if (o < (unsigned)kOvfCap) ovf[o] = v;  // kOvfCap=64K: cannot fill (P~0)
    }
}

// Clean main kernel: bare R6 body only -> 48 VGPR, 8 waves/SIMD reachable.
__global__ __launch_bounds__(256, 8) void hashenc_sorted(const f32x4* __restrict__ xsort,
                                                         const unsigned* __restrict__ cnt,
                                                         const f32x4* __restrict__ tab4base,
                                                         f32x4* __restrict__ out) {
    // chunked XCD swizzle: XCD k owns a contiguous Morton chunk (2048 = 8*256)
    const int bid = (int)((blockIdx.x & 7) * 256 + (blockIdx.x >> 3));
    const int gs  = bid * 256 + (int)threadIdx.x;
    const int bin = gs >> 7;          // kCap = 128
    const int sl  = gs & (kCap - 1);
    const unsigned n = min(cnt[bin], (unsigned)kCap);
    if ((unsigned)sl >= n) return;    // padded slots: wave exits/masks quickly
    const f32x4 v = xsort[gs];
    hashenc_body(v.x, v.y, v.z, tab4base, out, __float_as_uint(v.w));
}

// Overflow cleanup in its own dispatch (~always zero work; correctness net).
__global__ __launch_bounds__(256) void cleanup_kernel(const f32x4* __restrict__ ovf,
                                                      const unsigned* __restrict__ cnt,
                                                      const f32x4* __restrict__ tab4base,
                                                      f32x4* __restrict__ out) {
    const unsigned oc = min(cnt[kBins], (unsigned)kOvfCap);
    for (unsigned j = threadIdx.x; j < oc; j += 256) {
        const f32x4 v = ovf[j];
        hashenc_body(v.x, v.y, v.z, tab4base, out, __float_as_uint(v.w));
    }
}

__global__ __launch_bounds__(256, 4) void hashenc_direct(const float* __restrict__ x,
                                                         const f32x4* __restrict__ tab4base,
                                                         f32x4* __restrict__ out) {
    const int i = blockIdx.x * 256 + threadIdx.x;
    hashenc_body(x[3 * i], x[3 * i + 1], x[3 * i + 2], tab4base, out, (unsigned)i);
}

extern "C" void kernel_launch(void* const* d_in, const int* in_sizes, int n_in,
                              void* d_out, int out_size, void* d_ws, size_t ws_size,
                              hipStream_t stream) {
    const float*  x    = (const float*)d_in[0];
    const f32x4*  tab4 = (const f32x4*)d_in[1];
    f32x4*        out  = (f32x4*)d_out;

    const size_t cntBytes   = (size_t)(kBins + 16) * 4;       // counters + ovf count
    const size_t ovfBytes   = (size_t)kOvfCap * 16;           // 1 MB
    const size_t xsortBytes = (size_t)kBins * kCap * 16;      // 8 MB
    const size_t need = cntBytes + ovfBytes + xsortBytes;

    if (ws_size >= need) {
        unsigned* cnt   = (unsigned*)d_ws;
        f32x4*    ovf   = (f32x4*)((char*)d_ws + cntBytes);
        f32x4*    xsort = ovf + kOvfCap;
        hipMemsetAsync(cnt, 0, cntBytes, stream);
        scatter_kernel<<<kB / 256, 256, 0, stream>>>(x, cnt, xsort, ovf);
        hashenc_sorted<<<(kBins * kCap) / 256, 256, 0, stream>>>(xsort, cnt, tab4, out);
        cleanup_kernel<<<1, 256, 0, stream>>>(ovf, cnt, tab4, out);
    } else {
        hashenc_direct<<<kB / 256, 256, 0, stream>>>(x, tab4, out);
    }
}

// Round 10
// 157.315 us; speedup vs baseline: 1.2903x; 1.2903x over previous
//
#include <hip/hip_runtime.h>

// Multiresolution hash encoding, MI355X. Round 10.
// Config ledger (main body µs/VGPR/occ%): R6=133/48/27 (lb 256,4);
// R8=161/108/15 (ABI-pessimized); R9=203/32/46 (lb 256,8 register-starved ILP:
// a level needs 8 f32x4 loads in flight = 32 VGPR of destinations alone).
// Lesson: throughput = per-wave MLP, not wave count. This round: R6's exact
// main-kernel config (lb 256,4) + R9's free padded-bin preprocessing (~5us).

constexpr int      kT      = 524288;     // 2^19 rows per level
constexpr unsigned kMask   = kT - 1;
constexpr int      kB      = 262144;
constexpr unsigned kP1     = 2654435761u;
constexpr unsigned kP2     = 805459861u;
constexpr int      kBins   = 4096;
constexpr int      kCap    = 128;        // slots per bin (2 waves)
constexpr int      kOvfCap = 65536;      // overflow list capacity (never filled)

typedef float f32x4 __attribute__((ext_vector_type(4)));

__device__ __forceinline__ unsigned morton12(float x0, float x1, float x2) {
    unsigned a = min(15u, (unsigned)(x0 * 16.0f));
    unsigned b = min(15u, (unsigned)(x1 * 16.0f));
    unsigned c = min(15u, (unsigned)(x2 * 16.0f));
    unsigned key = 0;
#pragma unroll
    for (int i = 3; i >= 0; --i)
        key = (key << 3) | (((a >> i) & 1u) << 2) | (((b >> i) & 1u) << 1) | ((c >> i) & 1u);
    return key;
}

// ---- main compute body: R5/R6 pair-load structure (dim0 prime==1) ----
__device__ __forceinline__ void hashenc_body(const float x0, const float x1, const float x2,
                                             const f32x4* __restrict__ tab4base,
                                             f32x4* __restrict__ out, const unsigned sid) {
    f32x4 o[8];
    // floor(16 * b^l), b = 2^(1/3): rounding-traced, verified (absmax 4.8e-7)
    constexpr float kResF[16] = {16, 20, 25, 32, 40, 50, 64, 80,
                                 101, 128, 161, 203, 256, 322, 406, 512};
#pragma unroll
    for (int l = 0; l < 16; ++l) {
        const float res = kResF[l];
        const float s0 = x0 * res, s1 = x1 * res, s2 = x2 * res;
        const float f0 = floorf(s0), f1 = floorf(s1), f2 = floorf(s2);
        const float r0 = s0 - f0, r1 = s1 - f1, r2 = s2 - f2;
        const unsigned c0 = (unsigned)f0;
        const unsigned h1a = (unsigned)f1 * kP1, h1b = h1a + kP1;
        const unsigned h2a = (unsigned)f2 * kP2, h2b = h2a + kP2;
        const float w0a = 1.0f - r0, w1a = 1.0f - r1, w2a = 1.0f - r2;
        const f32x4* __restrict__ tab4 = tab4base + (size_t)l * (kT / 2);
        float a0 = 0.0f, a1 = 0.0f;
#pragma unroll
        for (int q = 0; q < 4; ++q) {  // (y,z) corner combos
            const unsigned g = ((q & 1) ? h1b : h1a) ^ ((q & 2) ? h2b : h2a);
            const unsigned i0 = (c0 ^ g) & kMask;
            const unsigned i1 = ((c0 + 1u) ^ g) & kMask;
            const f32x4 A = tab4[i0 >> 1];
            const f32x4 B = tab4[i1 >> 1];  // same line as A when c0 even
            const float p0x = (i0 & 1) ? A.z : A.x;
            const float p0y = (i0 & 1) ? A.w : A.y;
            const float p1x = (i1 & 1) ? B.z : B.x;
            const float p1y = (i1 & 1) ? B.w : B.y;
            const float wyz = ((q & 1) ? r1 : w1a) * ((q & 2) ? r2 : w2a);
            const float wl = wyz * w0a;
            const float wr = wyz * r0;
            a0 = fmaf(wl, p0x, fmaf(wr, p1x, a0));
            a1 = fmaf(wl, p0y, fmaf(wr, p1y, a1));
        }
        if (l & 1) { o[l >> 1].z = a0; o[l >> 1].w = a1; }
        else       { o[l >> 1].x = a0; o[l >> 1].y = a1; }
    }
    f32x4* op = out + (size_t)sid * 8;
#pragma unroll
    for (int k = 0; k < 8; ++k) __builtin_nontemporal_store(o[k], op + k);
}

__global__ __launch_bounds__(256) void scatter_kernel(const float* __restrict__ x,
                                                      unsigned* __restrict__ cnt,
                                                      f32x4* __restrict__ xsort,
                                                      f32x4* __restrict__ ovf) {
    const int i = blockIdx.x * 256 + threadIdx.x;
    const float x0 = x[3 * i], x1 = x[3 * i + 1], x2 = x[3 * i + 2];
    const unsigned key = morton12(x0, x1, x2);
    const unsigned slot = atomicAdd(&cnt[key], 1u);
    f32x4 v;
    v.x = x0; v.y = x1; v.z = x2; v.w = __uint_as_float((unsigned)i);
    if (slot < (unsigned)kCap) {
        xsort[key * kCap + slot] = v;
    } else {
        const unsigned o = atomicAdd(&cnt[kBins], 1u);
        if (o < (unsigned)kOvfCap) ovf[o] = v;  // kOvfCap=64K: cannot fill (P~0)
    }
}

// Main kernel: bare R6 body, R6's exact launch bounds (256,4) -> 48 VGPR, MLP intact.
__global__ __launch_bounds__(256, 4) void hashenc_sorted(const f32x4* __restrict__ xsort,
                                                         const unsigned* __restrict__ cnt,
                                                         const f32x4* __restrict__ tab4base,
                                                         f32x4* __restrict__ out) {
    // chunked XCD swizzle: XCD k owns a contiguous Morton chunk (2048 = 8*256)
    const int bid = (int)((blockIdx.x & 7) * 256 + (blockIdx.x >> 3));
    const int gs  = bid * 256 + (int)threadIdx.x;
    const int bin = gs >> 7;          // kCap = 128
    const int sl  = gs & (kCap - 1);
    const unsigned n = min(cnt[bin], (unsigned)kCap);
    if ((unsigned)sl >= n) return;    // padded slots: wave exits/masks quickly
    const f32x4 v = xsort[gs];
    hashenc_body(v.x, v.y, v.z, tab4base, out, __float_as_uint(v.w));
}

// Overflow cleanup in its own dispatch (~always zero work; correctness net).
__global__ __launch_bounds__(256) void cleanup_kernel(const f32x4* __restrict__ ovf,
                                                      const unsigned* __restrict__ cnt,
                                                      const f32x4* __restrict__ tab4base,
                                                      f32x4* __restrict__ out) {
    const unsigned oc = min(cnt[kBins], (unsigned)kOvfCap);
    for (unsigned j = threadIdx.x; j < oc; j += 256) {
        const f32x4 v = ovf[j];
        hashenc_body(v.x, v.y, v.z, tab4base, out, __float_as_uint(v.w));
    }
}

__global__ __launch_bounds__(256, 4) void hashenc_direct(const float* __restrict__ x,
                                                         const f32x4* __restrict__ tab4base,
                                                         f32x4* __restrict__ out) {
    const int i = blockIdx.x * 256 + threadIdx.x;
    hashenc_body(x[3 * i], x[3 * i + 1], x[3 * i + 2], tab4base, out, (unsigned)i);
}

extern "C" void kernel_launch(void* const* d_in, const int* in_sizes, int n_in,
                              void* d_out, int out_size, void* d_ws, size_t ws_size,
                              hipStream_t stream) {
    const float*  x    = (const float*)d_in[0];
    const f32x4*  tab4 = (const f32x4*)d_in[1];
    f32x4*        out  = (f32x4*)d_out;

    const size_t cntBytes   = (size_t)(kBins + 16) * 4;       // counters + ovf count
    const size_t ovfBytes   = (size_t)kOvfCap * 16;           // 1 MB
    const size_t xsortBytes = (size_t)kBins * kCap * 16;      // 8 MB
    const size_t need = cntBytes + ovfBytes + xsortBytes;

    if (ws_size >= need) {
        unsigned* cnt   = (unsigned*)d_ws;
        f32x4*    ovf   = (f32x4*)((char*)d_ws + cntBytes);
        f32x4*    xsort = ovf + kOvfCap;
        hipMemsetAsync(cnt, 0, cntBytes, stream);
        scatter_kernel<<<kB / 256, 256, 0, stream>>>(x, cnt, xsort, ovf);
        hashenc_sorted<<<(kBins * kCap) / 256, 256, 0, stream>>>(xsort, cnt, tab4, out);
        cleanup_kernel<<<1, 256, 0, stream>>>(ovf, cnt, tab4, out);
    } else {
        hashenc_direct<<<kB / 256, 256, 0, stream>>>(x, tab4, out);
    }
}

// Round 11
// 157.233 us; speedup vs baseline: 1.2910x; 1.0005x over previous
//
#include <hip/hip_runtime.h>

// Multiresolution hash encoding, MI355X. Round 11.
// R10 ledger (main µs/VGPR/occ%): (256,4)=133/48/29, (256,8)=203/32/46.
// Model: perf ~ outstanding miss-lines/CU = waves/CU x loads-in-flight/wave
// (latency x concurrency bound). 48 VGPR allows ~10 blocks/CU but lb(256,4)
// caps 4. This round, ONE change: drop the min-waves arg (lb(256) only) so
// the compiler keeps its natural ~48-VGPR schedule (8 loads in flight) and
// the HW packs ~8 blocks/CU -> ~2x outstanding misses.

constexpr int      kT      = 524288;     // 2^19 rows per level
constexpr unsigned kMask   = kT - 1;
constexpr int      kB      = 262144;
constexpr unsigned kP1     = 2654435761u;
constexpr unsigned kP2     = 805459861u;
constexpr int      kBins   = 4096;
constexpr int      kCap    = 128;        // slots per bin (2 waves)
constexpr int      kOvfCap = 65536;      // overflow list capacity (never filled)

typedef float f32x4 __attribute__((ext_vector_type(4)));

__device__ __forceinline__ unsigned morton12(float x0, float x1, float x2) {
    unsigned a = min(15u, (unsigned)(x0 * 16.0f));
    unsigned b = min(15u, (unsigned)(x1 * 16.0f));
    unsigned c = min(15u, (unsigned)(x2 * 16.0f));
    unsigned key = 0;
#pragma unroll
    for (int i = 3; i >= 0; --i)
        key = (key << 3) | (((a >> i) & 1u) << 2) | (((b >> i) & 1u) << 1) | ((c >> i) & 1u);
    return key;
}

// ---- main compute body: R5/R6 pair-load structure (dim0 prime==1) ----
__device__ __forceinline__ void hashenc_body(const float x0, const float x1, const float x2,
                                             const f32x4* __restrict__ tab4base,
                                             f32x4* __restrict__ out, const unsigned sid) {
    f32x4 o[8];
    // floor(16 * b^l), b = 2^(1/3): rounding-traced, verified (absmax 4.8e-7)
    constexpr float kResF[16] = {16, 20, 25, 32, 40, 50, 64, 80,
                                 101, 128, 161, 203, 256, 322, 406, 512};
#pragma unroll
    for (int l = 0; l < 16; ++l) {
        const float res = kResF[l];
        const float s0 = x0 * res, s1 = x1 * res, s2 = x2 * res;
        const float f0 = floorf(s0), f1 = floorf(s1), f2 = floorf(s2);
        const float r0 = s0 - f0, r1 = s1 - f1, r2 = s2 - f2;
        const unsigned c0 = (unsigned)f0;
        const unsigned h1a = (unsigned)f1 * kP1, h1b = h1a + kP1;
        const unsigned h2a = (unsigned)f2 * kP2, h2b = h2a + kP2;
        const float w0a = 1.0f - r0, w1a = 1.0f - r1, w2a = 1.0f - r2;
        const f32x4* __restrict__ tab4 = tab4base + (size_t)l * (kT / 2);
        float a0 = 0.0f, a1 = 0.0f;
#pragma unroll
        for (int q = 0; q < 4; ++q) {  // (y,z) corner combos
            const unsigned g = ((q & 1) ? h1b : h1a) ^ ((q & 2) ? h2b : h2a);
            const unsigned i0 = (c0 ^ g) & kMask;
            const unsigned i1 = ((c0 + 1u) ^ g) & kMask;
            const f32x4 A = tab4[i0 >> 1];
            const f32x4 B = tab4[i1 >> 1];  // same line as A when c0 even
            const float p0x = (i0 & 1) ? A.z : A.x;
            const float p0y = (i0 & 1) ? A.w : A.y;
            const float p1x = (i1 & 1) ? B.z : B.x;
            const float p1y = (i1 & 1) ? B.w : B.y;
            const float wyz = ((q & 1) ? r1 : w1a) * ((q & 2) ? r2 : w2a);
            const float wl = wyz * w0a;
            const float wr = wyz * r0;
            a0 = fmaf(wl, p0x, fmaf(wr, p1x, a0));
            a1 = fmaf(wl, p0y, fmaf(wr, p1y, a1));
        }
        if (l & 1) { o[l >> 1].z = a0; o[l >> 1].w = a1; }
        else       { o[l >> 1].x = a0; o[l >> 1].y = a1; }
    }
    f32x4* op = out + (size_t)sid * 8;
#pragma unroll
    for (int k = 0; k < 8; ++k) __builtin_nontemporal_store(o[k], op + k);
}

__global__ __launch_bounds__(256) void scatter_kernel(const float* __restrict__ x,
                                                      unsigned* __restrict__ cnt,
                                                      f32x4* __restrict__ xsort,
                                                      f32x4* __restrict__ ovf) {
    const int i = blockIdx.x * 256 + threadIdx.x;
    const float x0 = x[3 * i], x1 = x[3 * i + 1], x2 = x[3 * i + 2];
    const unsigned key = morton12(x0, x1, x2);
    const unsigned slot = atomicAdd(&cnt[key], 1u);
    f32x4 v;
    v.x = x0; v.y = x1; v.z = x2; v.w = __uint_as_float((unsigned)i);
    if (slot < (unsigned)kCap) {
        xsort[key * kCap + slot] = v;
    } else {
        const unsigned o = atomicAdd(&cnt[kBins], 1u);
        if (o < (unsigned)kOvfCap) ovf[o] = v;  // kOvfCap=64K: cannot fill (P~0)
    }
}

// Main kernel: bare R6 body; NO min-waves constraint -> compiler keeps its
// natural ILP schedule (~48 VGPR), HW packs up to 8 blocks/CU.
__global__ __launch_bounds__(256) void hashenc_sorted(const f32x4* __restrict__ xsort,
                                                      const unsigned* __restrict__ cnt,
                                                      const f32x4* __restrict__ tab4base,
                                                      f32x4* __restrict__ out) {
    // chunked XCD swizzle: XCD k owns a contiguous Morton chunk (2048 = 8*256)
    const int bid = (int)((blockIdx.x & 7) * 256 + (blockIdx.x >> 3));
    const int gs  = bid * 256 + (int)threadIdx.x;
    const int bin = gs >> 7;          // kCap = 128
    const int sl  = gs & (kCap - 1);
    const unsigned n = min(cnt[bin], (unsigned)kCap);
    if ((unsigned)sl >= n) return;    // padded slots: wave exits/masks quickly
    const f32x4 v = xsort[gs];
    hashenc_body(v.x, v.y, v.z, tab4base, out, __float_as_uint(v.w));
}

// Overflow cleanup in its own dispatch (~always zero work; correctness net).
__global__ __launch_bounds__(256) void cleanup_kernel(const f32x4* __restrict__ ovf,
                                                      const unsigned* __restrict__ cnt,
                                                      const f32x4* __restrict__ tab4base,
                                                      f32x4* __restrict__ out) {
    const unsigned oc = min(cnt[kBins], (unsigned)kOvfCap);
    for (unsigned j = threadIdx.x; j < oc; j += 256) {
        const f32x4 v = ovf[j];
        hashenc_body(v.x, v.y, v.z, tab4base, out, __float_as_uint(v.w));
    }
}

__global__ __launch_bounds__(256, 4) void hashenc_direct(const float* __restrict__ x,
                                                         const f32x4* __restrict__ tab4base,
                                                         f32x4* __restrict__ out) {
    const int i = blockIdx.x * 256 + threadIdx.x;
    hashenc_body(x[3 * i], x[3 * i + 1], x[3 * i + 2], tab4base, out, (unsigned)i);
}

extern "C" void kernel_launch(void* const* d_in, const int* in_sizes, int n_in,
                              void* d_out, int out_size, void* d_ws, size_t ws_size,
                              hipStream_t stream) {
    const float*  x    = (const float*)d_in[0];
    const f32x4*  tab4 = (const f32x4*)d_in[1];
    f32x4*        out  = (f32x4*)d_out;

    const size_t cntBytes   = (size_t)(kBins + 16) * 4;       // counters + ovf count
    const size_t ovfBytes   = (size_t)kOvfCap * 16;           // 1 MB
    const size_t xsortBytes = (size_t)kBins * kCap * 16;      // 8 MB
    const size_t need = cntBytes + ovfBytes + xsortBytes;

    if (ws_size >= need) {
        unsigned* cnt   = (unsigned*)d_ws;
        f32x4*    ovf   = (f32x4*)((char*)d_ws + cntBytes);
        f32x4*    xsort = ovf + kOvfCap;
        hipMemsetAsync(cnt, 0, cntBytes, stream);
        scatter_kernel<<<kB / 256, 256, 0, stream>>>(x, cnt, xsort, ovf);
        hashenc_sorted<<<(kBins * kCap) / 256, 256, 0, stream>>>(xsort, cnt, tab4, out);
        cleanup_kernel<<<1, 256, 0, stream>>>(ovf, cnt, tab4, out);
    } else {
        hashenc_direct<<<kB / 256, 256, 0, stream>>>(x, tab4, out);
    }
}

// Round 12
// 155.404 us; speedup vs baseline: 1.3061x; 1.0118x over previous
//
#include <hip/hip_runtime.h>

// Multiresolution hash encoding, MI355X. Round 12: cooperative coarse levels.
// Cost model (fit R5 vs R6/R10): ~0.8 cyc/lane-address (TA, no duplicate
// compression) + ~2 cyc/L1-fill-line. Sorted waves = one 1/16-brick, so for
// res<=64 (exc. 50) the wave's full corner set (N^3<=125, wave-uniform from
// bin id) is gathered cooperatively once (413 addrs vs 3072) into per-wave
// LDS; lanes trilinear from LDS. Fine levels keep the R5 pair-load path.
// Partial waves: lanes stay alive (x=0.5 + clamps, masked store) -- no
// divergent-liveness regalloc trap (R7 lesson).

constexpr int      kT      = 524288;     // 2^19 rows per level
constexpr unsigned kMask   = kT - 1;
constexpr int      kB      = 262144;
constexpr unsigned kP1     = 2654435761u;
constexpr unsigned kP2     = 805459861u;
constexpr int      kBins   = 4096;
constexpr int      kCap    = 128;        // slots per bin (2 waves)
constexpr int      kOvfCap = 65536;      // overflow list capacity (never filled)
constexpr int      kCoopTot = 413;       // per-wave LDS f32x2 entries

typedef float f32x4 __attribute__((ext_vector_type(4)));
typedef float f32x2 __attribute__((ext_vector_type(2)));

__device__ __forceinline__ unsigned morton12(float x0, float x1, float x2) {
    unsigned a = min(15u, (unsigned)(x0 * 16.0f));
    unsigned b = min(15u, (unsigned)(x1 * 16.0f));
    unsigned c = min(15u, (unsigned)(x2 * 16.0f));
    unsigned key = 0;
#pragma unroll
    for (int i = 3; i >= 0; --i)
        key = (key << 3) | (((a >> i) & 1u) << 2) | (((b >> i) & 1u) << 1) | ((c >> i) & 1u);
    return key;
}

// ---- direct path: one level, pair-load structure (dim0 prime==1) ----
__device__ __forceinline__ f32x2 direct_level(const float x0, const float x1, const float x2,
                                              const float res,
                                              const f32x4* __restrict__ tab4) {
    const float s0 = x0 * res, s1 = x1 * res, s2 = x2 * res;
    const float f0 = floorf(s0), f1 = floorf(s1), f2 = floorf(s2);
    const float r0 = s0 - f0, r1 = s1 - f1, r2 = s2 - f2;
    const unsigned c0 = (unsigned)f0;
    const unsigned h1a = (unsigned)f1 * kP1, h1b = h1a + kP1;
    const unsigned h2a = (unsigned)f2 * kP2, h2b = h2a + kP2;
    const float w0a = 1.0f - r0, w1a = 1.0f - r1, w2a = 1.0f - r2;
    float a0 = 0.0f, a1 = 0.0f;
#pragma unroll
    for (int q = 0; q < 4; ++q) {  // (y,z) corner combos
        const unsigned g = ((q & 1) ? h1b : h1a) ^ ((q & 2) ? h2b : h2a);
        const unsigned i0 = (c0 ^ g) & kMask;
        const unsigned i1 = ((c0 + 1u) ^ g) & kMask;
        const f32x4 A = tab4[i0 >> 1];
        const f32x4 B = tab4[i1 >> 1];  // same line as A when c0 even
        const float p0x = (i0 & 1) ? A.z : A.x;
        const float p0y = (i0 & 1) ? A.w : A.y;
        const float p1x = (i1 & 1) ? B.z : B.x;
        const float p1y = (i1 & 1) ? B.w : B.y;
        const float wyz = ((q & 1) ? r1 : w1a) * ((q & 2) ? r2 : w2a);
        const float wl = wyz * w0a;
        const float wr = wyz * r0;
        a0 = fmaf(wl, p0x, fmaf(wr, p1x, a0));
        a1 = fmaf(wl, p0y, fmaf(wr, p1y, a1));
    }
    f32x2 r; r.x = a0; r.y = a1;
    return r;
}

// ---- full 16-level direct body (fallback / cleanup paths) ----
__device__ __forceinline__ void hashenc_body(const float x0, const float x1, const float x2,
                                             const f32x4* __restrict__ tab4base,
                                             f32x4* __restrict__ out, const unsigned sid) {
    f32x4 o[8];
    // floor(16 * b^l), b = 2^(1/3): rounding-traced, verified (absmax 4.8e-7)
    constexpr float kResF[16] = {16, 20, 25, 32, 40, 50, 64, 80,
                                 101, 128, 161, 203, 256, 322, 406, 512};
#pragma unroll
    for (int l = 0; l < 16; ++l) {
        const f32x2 r = direct_level(x0, x1, x2, kResF[l], tab4base + (size_t)l * (kT / 2));
        if (l & 1) { o[l >> 1].z = r.x; o[l >> 1].w = r.y; }
        else       { o[l >> 1].x = r.x; o[l >> 1].y = r.y; }
    }
    f32x4* op = out + (size_t)sid * 8;
#pragma unroll
    for (int k = 0; k < 8; ++k) __builtin_nontemporal_store(o[k], op + k);
}

// ---- cooperative coarse-level helpers ----
template <int L, int N, int RES, int OFF>
__device__ __forceinline__ void coop_fill(const unsigned lane,
                                          const unsigned bx, const unsigned by, const unsigned bz,
                                          const f32x2* __restrict__ tab2,
                                          f32x2* __restrict__ wlds) {
    const unsigned lo0 = (bx * RES) >> 4, lo1 = (by * RES) >> 4, lo2 = (bz * RES) >> 4;
    const unsigned h1 = lo1 * kP1, h2 = lo2 * kP2;
    constexpr int NC = N * N * N;
#pragma unroll
    for (int k = 0; k < (NC + 63) / 64; ++k) {
        const int t = (int)lane + 64 * k;
        if (t < NC) {
            const unsigned dx = (unsigned)t / (N * N);
            const unsigned rem = (unsigned)t % (N * N);
            const unsigned dy = rem / N, dz = rem % N;
            const unsigned idx = ((lo0 + dx) ^ (h1 + dy * kP1) ^ (h2 + dz * kP2)) & kMask;
            wlds[OFF + t] = tab2[(size_t)L * kT + idx];
        }
    }
}

template <int N, int RES, int OFF>
__device__ __forceinline__ f32x2 coop_interp(const float x0, const float x1, const float x2,
                                             const unsigned bx, const unsigned by, const unsigned bz,
                                             const f32x2* __restrict__ wlds) {
    const float res = (float)RES;
    const float s0 = x0 * res, s1 = x1 * res, s2 = x2 * res;
    const float f0 = floorf(s0), f1 = floorf(s1), f2 = floorf(s2);
    const float r0 = s0 - f0, r1 = s1 - f1, r2 = s2 - f2;
    const unsigned lo0 = (bx * RES) >> 4, lo1 = (by * RES) >> 4, lo2 = (bz * RES) >> 4;
    // valid lanes: indices provably in [0, N-2]; min() only guards garbage lanes
    const unsigned i0 = min((unsigned)f0 - lo0, (unsigned)(N - 2));
    const unsigned i1 = min((unsigned)f1 - lo1, (unsigned)(N - 2));
    const unsigned i2 = min((unsigned)f2 - lo2, (unsigned)(N - 2));
    const int s00 = OFF + (int)(i0 * (N * N) + i1 * N + i2);
    const f32x2 c000 = wlds[s00],             c001 = wlds[s00 + 1];
    const f32x2 c010 = wlds[s00 + N],         c011 = wlds[s00 + N + 1];
    const f32x2 c100 = wlds[s00 + N * N],     c101 = wlds[s00 + N * N + 1];
    const f32x2 c110 = wlds[s00 + N * N + N], c111 = wlds[s00 + N * N + N + 1];
    const float w0a = 1.f - r0, w1a = 1.f - r1, w2a = 1.f - r2;
    float a0, a1;
    const float w00 = w0a * w1a, w01 = w0a * r1, w10 = r0 * w1a, w11 = r0 * r1;
    a0 = w00 * w2a * c000.x; a1 = w00 * w2a * c000.y;
    a0 = fmaf(w00 * r2, c001.x, a0); a1 = fmaf(w00 * r2, c001.y, a1);
    a0 = fmaf(w01 * w2a, c010.x, a0); a1 = fmaf(w01 * w2a, c010.y, a1);
    a0 = fmaf(w01 * r2, c011.x, a0); a1 = fmaf(w01 * r2, c011.y, a1);
    a0 = fmaf(w10 * w2a, c100.x, a0); a1 = fmaf(w10 * w2a, c100.y, a1);
    a0 = fmaf(w10 * r2, c101.x, a0); a1 = fmaf(w10 * r2, c101.y, a1);
    a0 = fmaf(w11 * w2a, c110.x, a0); a1 = fmaf(w11 * r2 / r2 * r2, 0.f, a1);  // placeholder fixed below
    // (rewritten cleanly below to avoid mistakes)
    a1 = fmaf(w11 * w2a, c110.y, fmaf(w10 * r2, c101.y, fmaf(w10 * w2a, c100.y,
         fmaf(w01 * r2, c011.y, fmaf(w01 * w2a, c010.y, fmaf(w00 * r2, c001.y, w00 * w2a * c000.y))))));
    a0 = fmaf(w11 * w2a, c110.x, fmaf(w10 * r2, c101.x, fmaf(w10 * w2a, c100.x,
         fmaf(w01 * r2, c011.x, fmaf(w01 * w2a, c010.x, fmaf(w00 * r2, c001.x, w00 * w2a * c000.x))))));
    a0 = fmaf(w11 * r2, c111.x, a0);
    a1 = fmaf(w11 * r2, c111.y, a1);
    f32x2 r; r.x = a0; r.y = a1;
    return r;
}

__global__ __launch_bounds__(256) void scatter_kernel(const float* __restrict__ x,
                                                      unsigned* __restrict__ cnt,
                                                      f32x4* __restrict__ xsort,
                                                      f32x4* __restrict__ ovf) {
    const int i = blockIdx.x * 256 + threadIdx.x;
    const float x0 = x[3 * i], x1 = x[3 * i + 1], x2 = x[3 * i + 2];
    const unsigned key = morton12(x0, x1, x2);
    const unsigned slot = atomicAdd(&cnt[key], 1u);
    f32x4 v;
    v.x = x0; v.y = x1; v.z = x2; v.w = __uint_as_float((unsigned)i);
    if (slot < (unsigned)kCap) {
        xsort[key * kCap + slot] = v;
    } else {
        const unsigned o = atomicAdd(&cnt[kBins], 1u);
        if (o < (unsigned)kOvfCap) ovf[o] = v;  // kOvfCap=64K: cannot fill (P~0)
    }
}

__global__ __launch_bounds__(256) void hashenc_sorted(const f32x4* __restrict__ xsort,
                                                      const unsigned* __restrict__ cnt,
                                                      const f32x2* __restrict__ tab2,
                                                      const f32x4* __restrict__ tab4base,
                                                      f32x4* __restrict__ out) {
    __shared__ f32x2 lds[4][kCoopTot];
    const int tid = threadIdx.x;
    // chunked XCD swizzle: XCD k owns a contiguous Morton chunk (2048 = 8*256)
    const int bid = (int)((blockIdx.x & 7) * 256 + (blockIdx.x >> 3));
    const int gs  = bid * 256 + tid;
    const int bin = gs >> 7;          // kCap = 128
    const int sl  = gs & (kCap - 1);
    const unsigned n = min(cnt[bin], (unsigned)kCap);
    if ((unsigned)(sl & 64) >= n) return;   // wave-uniform early out (wave's min slot)
    const bool valid = (unsigned)sl < n;
    const f32x4 v = xsort[gs];
    const float x0 = valid ? v.x : 0.5f;    // garbage lanes -> benign coords
    const float x1 = valid ? v.y : 0.5f;
    const float x2 = valid ? v.z : 0.5f;

    // bin coords from morton key (wave-uniform)
    const unsigned key = (unsigned)bin;
    const unsigned bx = ((key >> 2) & 1) | ((key >> 4) & 2) | ((key >> 6) & 4) | ((key >> 8) & 8);
    const unsigned by = ((key >> 1) & 1) | ((key >> 3) & 2) | ((key >> 5) & 4) | ((key >> 7) & 8);
    const unsigned bz = ((key     ) & 1) | ((key >> 2) & 2) | ((key >> 4) & 4) | ((key >> 6) & 8);

    f32x2* wlds = lds[tid >> 6];
    const unsigned lane = (unsigned)(tid & 63);
    // cooperative corner gathers: levels {0,1,2,3,4,6}, 413 addrs total
    coop_fill<0, 2, 16, 0>(lane, bx, by, bz, tab2, wlds);
    coop_fill<1, 4, 20, 8>(lane, bx, by, bz, tab2, wlds);
    coop_fill<2, 4, 25, 72>(lane, bx, by, bz, tab2, wlds);
    coop_fill<3, 3, 32, 136>(lane, bx, by, bz, tab2, wlds);
    coop_fill<4, 5, 40, 163>(lane, bx, by, bz, tab2, wlds);
    coop_fill<6, 5, 64, 288>(lane, bx, by, bz, tab2, wlds);

    f32x4 o[8];
    // direct levels: res50 (l=5) + l=7..15
    { const f32x2 r = direct_level(x0, x1, x2, 50.f,  tab4base + (size_t)5  * (kT / 2)); o[2].z = r.x; o[2].w = r.y; }
    { const f32x2 r = direct_level(x0, x1, x2, 80.f,  tab4base + (size_t)7  * (kT / 2)); o[3].z = r.x; o[3].w = r.y; }
    { const f32x2 r = direct_level(x0, x1, x2, 101.f, tab4base + (size_t)8  * (kT / 2)); o[4].x = r.x; o[4].y = r.y; }
    { const f32x2 r = direct_level(x0, x1, x2, 128.f, tab4base + (size_t)9  * (kT / 2)); o[4].z = r.x; o[4].w = r.y; }
    { const f32x2 r = direct_level(x0, x1, x2, 161.f, tab4base + (size_t)10 * (kT / 2)); o[5].x = r.x; o[5].y = r.y; }
    { const f32x2 r = direct_level(x0, x1, x2, 203.f, tab4base + (size_t)11 * (kT / 2)); o[5].z = r.x; o[5].w = r.y; }
    { const f32x2 r = direct_level(x0, x1, x2, 256.f, tab4base + (size_t)12 * (kT / 2)); o[6].x = r.x; o[6].y = r.y; }
    { const f32x2 r = direct_level(x0, x1, x2, 322.f, tab4base + (size_t)13 * (kT / 2)); o[6].z = r.x; o[6].w = r.y; }
    { const f32x2 r = direct_level(x0, x1, x2, 406.f, tab4base + (size_t)14 * (kT / 2)); o[7].x = r.x; o[7].y = r.y; }
    { const f32x2 r = direct_level(x0, x1, x2, 512.f, tab4base + (size_t)15 * (kT / 2)); o[7].z = r.x; o[7].w = r.y; }
    // coop consumes (LDS)
    { const f32x2 r = coop_interp<2, 16, 0>(x0, x1, x2, bx, by, bz, wlds);   o[0].x = r.x; o[0].y = r.y; }
    { const f32x2 r = coop_interp<4, 20, 8>(x0, x1, x2, bx, by, bz, wlds);   o[0].z = r.x; o[0].w = r.y; }
    { const f32x2 r = coop_interp<4, 25, 72>(x0, x1, x2, bx, by, bz, wlds);  o[1].x = r.x; o[1].y = r.y; }
    { const f32x2 r = coop_interp<3, 32, 136>(x0, x1, x2, bx, by, bz, wlds); o[1].z = r.x; o[1].w = r.y; }
    { const f32x2 r = coop_interp<5, 40, 163>(x0, x1, x2, bx, by, bz, wlds); o[2].x = r.x; o[2].y = r.y; }
    { const f32x2 r = coop_interp<5, 64, 288>(x0, x1, x2, bx, by, bz, wlds); o[3].x = r.x; o[3].y = r.y; }

    if (valid) {
        f32x4* op = out + (size_t)__float_as_uint(v.w) * 8;
#pragma unroll
        for (int k = 0; k < 8; ++k) __builtin_nontemporal_store(o[k], op + k);
    }
}

// Overflow cleanup in its own dispatch (~always zero work; correctness net).
__global__ __launch_bounds__(256) void cleanup_kernel(const f32x4* __restrict__ ovf,
                                                      const unsigned* __restrict__ cnt,
                                                      const f32x4* __restrict__ tab4base,
                                                      f32x4* __restrict__ out) {
    const unsigned oc = min(cnt[kBins], (unsigned)kOvfCap);
    for (unsigned j = threadIdx.x; j < oc; j += 256) {
        const f32x4 v = ovf[j];
        hashenc_body(v.x, v.y, v.z, tab4base, out, __float_as_uint(v.w));
    }
}

__global__ __launch_bounds__(256, 4) void hashenc_direct(const float* __restrict__ x,
                                                         const f32x4* __restrict__ tab4base,
                                                         f32x4* __restrict__ out) {
    const int i = blockIdx.x * 256 + threadIdx.x;
    hashenc_body(x[3 * i], x[3 * i + 1], x[3 * i + 2], tab4base, out, (unsigned)i);
}

extern "C" void kernel_launch(void* const* d_in, const int* in_sizes, int n_in,
                              void* d_out, int out_size, void* d_ws, size_t ws_size,
                              hipStream_t stream) {
    const float*  x    = (const float*)d_in[0];
    const f32x2*  tab2 = (const f32x2*)d_in[1];
    const f32x4*  tab4 = (const f32x4*)d_in[1];
    f32x4*        out  = (f32x4*)d_out;

    const size_t cntBytes   = (size_t)(kBins + 16) * 4;       // counters + ovf count
    const size_t ovfBytes   = (size_t)kOvfCap * 16;           // 1 MB
    const size_t xsortBytes = (size_t)kBins * kCap * 16;      // 8 MB
    const size_t need = cntBytes + ovfBytes + xsortBytes;

    if (ws_size >= need) {
        unsigned* cnt   = (unsigned*)d_ws;
        f32x4*    ovf   = (f32x4*)((char*)d_ws + cntBytes);
        f32x4*    xsort = ovf + kOvfCap;
        hipMemsetAsync(cnt, 0, cntBytes, stream);
        scatter_kernel<<<kB / 256, 256, 0, stream>>>(x, cnt, xsort, ovf);
        hashenc_sorted<<<(kBins * kCap) / 256, 256, 0, stream>>>(xsort, cnt, tab2, tab4, out);
        cleanup_kernel<<<1, 256, 0, stream>>>(ovf, cnt, tab4, out);
    } else {
        hashenc_direct<<<kB / 256, 256, 0, stream>>>(x, tab4, out);
    }
}